// Round 3
// baseline (3927.984 us; speedup 1.0000x reference)
//
#include <hip/hip_runtime.h>

// T=256, B=128, H=2048. M = T*B = 32768.
// ws layout (bytes):
//   WT_in  @ 134217728  : 8388608     (w_in^T bf16, [n][k])
//   WT_rec @ 142606336  : 8388608     (w_rec^T bf16, [n][k])
//   hA     @ 150994944  : 524288      (h fragments, even t)
//   hB     @ 151519232  : 524288      (h fragments, odd t)
//   BAR    @ 152043520  : 32768       (ready flags 16 KB | consumed flags 16 KB)
//
// h fragment layout (A-operand-major, mfma 16x16x32):
//   frag f = (g*64 + kb)*2 + half  -> 1 KB block;  within: lane*16B + j*2B
//   element: row = 32g + 16*half + (lane&15), k = 32*kb + 8*(lane>>4) + j
// A consumer wave reads lane-contiguous 16 B per fragment (coalesced).
//
// ROUND 1 CHANGE: xproj fused into rnn_scan. Each wave holds its K-slice of
// w_in^T (32 cols x 512 k) in 128 VGPRs, computes x[t] @ w_in into the same
// accumulators BEFORE polling for h@{t-1} (fills the ~4 us/step wait slack).
// Sync protocol unchanged. XP buffer + xproj_gemm kernel deleted.

typedef __bf16 bf16x8 __attribute__((ext_vector_type(8)));
typedef float f32x4 __attribute__((ext_vector_type(4)));
typedef unsigned long long ullx2 __attribute__((ext_vector_type(2)));

__device__ __forceinline__ unsigned short f32_to_bf16(float f) {
    unsigned int u = __builtin_bit_cast(unsigned int, f);
    u += 0x7FFFu + ((u >> 16) & 1u);   // round-to-nearest-even
    return (unsigned short)(u >> 16);
}
__device__ __forceinline__ float bf16_to_f32(unsigned short s) {
    unsigned int u = ((unsigned int)s) << 16;
    return __builtin_bit_cast(float, u);
}
__device__ __forceinline__ bf16x8 cvt8(float4 a, float4 b) {
    uint4 r;
    r.x = (unsigned int)f32_to_bf16(a.x) | ((unsigned int)f32_to_bf16(a.y) << 16);
    r.y = (unsigned int)f32_to_bf16(a.z) | ((unsigned int)f32_to_bf16(a.w) << 16);
    r.z = (unsigned int)f32_to_bf16(b.x) | ((unsigned int)f32_to_bf16(b.y) << 16);
    r.w = (unsigned int)f32_to_bf16(b.z) | ((unsigned int)f32_to_bf16(b.w) << 16);
    return __builtin_bit_cast(bf16x8, r);
}

// ---------------------------------------------------------------------------
// Kernel 1: fp32 (2048x2048, [k][n]) -> bf16 transposed ([n][k]) via LDS tile.
// ---------------------------------------------------------------------------
__global__ __launch_bounds__(256)
void cvt_transpose(const float* __restrict__ W, unsigned short* __restrict__ WT) {
    __shared__ unsigned short tile[64][68];
    const int tid = threadIdx.x;
    const int n0 = (blockIdx.x & 31) * 64;
    const int k0 = (blockIdx.x >> 5) * 64;
    const int rr = tid >> 4;
    const int cc = (tid & 15) * 4;
#pragma unroll
    for (int p = 0; p < 4; ++p) {
        const int k = rr + p * 16;
        const float4 v = *(const float4*)(W + (size_t)(k0 + k) * 2048 + n0 + cc);
        tile[cc + 0][k] = f32_to_bf16(v.x);
        tile[cc + 1][k] = f32_to_bf16(v.y);
        tile[cc + 2][k] = f32_to_bf16(v.z);
        tile[cc + 3][k] = f32_to_bf16(v.w);
    }
    __syncthreads();
#pragma unroll
    for (int p = 0; p < 4; ++p) {
        const int n = rr + p * 16;
        unsigned int lo = (unsigned int)tile[n][cc]     | ((unsigned int)tile[n][cc + 1] << 16);
        unsigned int hi = (unsigned int)tile[n][cc + 2] | ((unsigned int)tile[n][cc + 3] << 16);
        uint2 ov; ov.x = lo; ov.y = hi;
        *(uint2*)(WT + (size_t)(n0 + n) * 2048 + k0 + cc) = ov;
    }
}

// ---------------------------------------------------------------------------
// Kernel 2: persistent recurrence + fused xproj.
// 256 blocks x 256 threads. g = (bid&7)>>1 (XCD-affine batch group),
// nb = column block 0..63. Wave w consumes kb in [16w,16w+16) -> produced by
// blocks nb=kb. h moves via coalesced 8B relaxed agent atomics (L3-coherent).
// Ws (w_rec) in LDS fragment-major; w_in slice in registers (128 VGPR/lane).
// Flags: rdy[g][nb]=t+1 (h@t at L3), cns[g][nb]=t (done reading h@{t-1}).
// ---------------------------------------------------------------------------
__global__ __launch_bounds__(256, 1)
void rnn_scan(const float* __restrict__ X,
              const unsigned short* __restrict__ WTin,
              const unsigned short* __restrict__ WT,
              const float* __restrict__ bias,
              unsigned short* __restrict__ hA,
              unsigned short* __restrict__ hB,
              float* __restrict__ out,
              unsigned int* __restrict__ bar) {
    __shared__ unsigned short Ws[64 * 2 * 512];   // w_rec fragment-major, 128 KB
    __shared__ float red[4 * 1024];               // 4 wave-partials of 32x32
    const int tid  = threadIdx.x;
    const int bid  = blockIdx.x;
    const int g    = (bid & 7) >> 1;               // batch group (XCD-affine)
    const int nb   = ((bid >> 3) << 1) | (bid & 1);// column block 0..63
    const int n0   = nb * 32;
    const int m0   = g * 32;
    const int lane = tid & 63;
    const int wave = tid >> 6;
    const int lcol = lane & 15;
    const int quad = lane >> 4;

    unsigned int* rdy_own = bar + (g * 64 + nb) * 16;
    unsigned int* cns_own = bar + 4096 + (g * 64 + nb) * 16;
    const unsigned int* rdy_poll = bar + (g * 64 + wave * 16 + lcol) * 16;  // my chunk's producers
    const unsigned int* cns_poll = bar + 4096 + (g * 64 + lane) * 16;       // all 64 group blocks

    // stage w_rec^T slice into LDS in B-fragment-major layout:
    // frag (kb, half): lane L holds B[n = 16*half + (L&15)][k = 32*kb + 8*(L>>4) + j]
    {
        const int r    = tid >> 3;          // local col n 0..31
        const int half = r >> 4;
        const int lc   = r & 15;
        const int ch   = (tid & 7) * 256;   // k start
        const unsigned short* src = WT + (size_t)(n0 + r) * 2048 + ch;
#pragma unroll
        for (int c = 0; c < 32; ++c) {
            const int k    = ch + c * 8;
            const int kb   = k >> 5;
            const int qd   = (k & 31) >> 3;
            unsigned short* dst = Ws + (kb * 2 + half) * 512 + (qd * 16 + lc) * 8;
            *(uint4*)dst = *(const uint4*)(src + c * 8);
        }
    }
    // w_in^T slice for THIS wave into registers, mirroring the B-frag layout:
    // win[kb][half]: lane L holds B[n = n0 + 16*half + (L&15)][k = 512*wave + 32*kb + 8*(L>>4) + j]
    bf16x8 win[16][2];
#pragma unroll
    for (int kb = 0; kb < 16; ++kb)
#pragma unroll
        for (int hf = 0; hf < 2; ++hf)
            win[kb][hf] = __builtin_bit_cast(bf16x8,
                *(const uint4*)(WTin + (size_t)(n0 + 16 * hf + lcol) * 2048
                                + 512 * wave + 32 * kb + 8 * quad));

    const int erow = tid >> 3;          // epilogue: 4 elems per thread
    const int ecol = (tid & 7) * 4;
    const float4 b4 = *(const float4*)(bias + n0 + ecol);
    // producer store offset (shorts) into fragment-major h
    const size_t hoff = ((size_t)(g * 64 + nb) * 2 + (erow >> 4)) * 512
                        + (size_t)((ecol >> 3) * 16 + (erow & 15)) * 8 + (ecol & 7);
    // consumer load base (ull units): frags (g, kb=wave*16+it, half)
    const size_t s0 = (size_t)(g * 64 + wave * 16) * 256 + lane * 2;
    __syncthreads();

    for (int t = 0; t < 256; ++t) {
        f32x4 a00 = {}, a01 = {}, a10 = {}, a11 = {};
        // ---- fused xproj: x[t, m0+row, 512w..512w+512) @ win -> acc init ----
        // Independent of h -> executes in the rdy-poll wait slack.
        {
            const float* xr0 = X + ((size_t)(t * 128 + m0 + lcol)) * 2048
                               + 512 * wave + 8 * quad;
            const float* xr1 = X + ((size_t)(t * 128 + m0 + 16 + lcol)) * 2048
                               + 512 * wave + 8 * quad;
#pragma unroll
            for (int kb = 0; kb < 16; ++kb) {
                const float4 u0 = *(const float4*)(xr0 + kb * 32);
                const float4 u1 = *(const float4*)(xr0 + kb * 32 + 4);
                const float4 v0 = *(const float4*)(xr1 + kb * 32);
                const float4 v1 = *(const float4*)(xr1 + kb * 32 + 4);
                const bf16x8 xa0 = cvt8(u0, u1);
                const bf16x8 xa1 = cvt8(v0, v1);
                a00 = __builtin_amdgcn_mfma_f32_16x16x32_bf16(xa0, win[kb][0], a00, 0, 0, 0);
                a01 = __builtin_amdgcn_mfma_f32_16x16x32_bf16(xa0, win[kb][1], a01, 0, 0, 0);
                a10 = __builtin_amdgcn_mfma_f32_16x16x32_bf16(xa1, win[kb][0], a10, 0, 0, 0);
                a11 = __builtin_amdgcn_mfma_f32_16x16x32_bf16(xa1, win[kb][1], a11, 0, 0, 0);
            }
        }
        // ---- recurrence: h@{t-1} @ w_rec accumulates into the same regs ----
        if (t > 0) {
            // wait for MY chunk's 16 producers to have h@{t-1} at L3
            while (__hip_atomic_load(rdy_poll, __ATOMIC_RELAXED, __HIP_MEMORY_SCOPE_AGENT) < (unsigned)t)
                __builtin_amdgcn_s_sleep(1);
            __builtin_amdgcn_fence(__ATOMIC_ACQUIRE, "workgroup");

            const unsigned long long* hp =
                (const unsigned long long*)((t & 1) ? hA : hB);
            const unsigned long long* a0p = hp + s0;          // half 0
            const unsigned long long* a1p = hp + s0 + 128;    // half 1
            const unsigned short* b0p = Ws + (wave * 16 * 2) * 512 + lane * 8;  // half 0
            const unsigned short* b1p = b0p + 512;                              // half 1
#pragma unroll
            for (int it = 0; it < 16; ++it) {
                const size_t ao = (size_t)it * 256;
                ullx2 u0, u1;
                u0.x = __hip_atomic_load(a0p + ao,     __ATOMIC_RELAXED, __HIP_MEMORY_SCOPE_AGENT);
                u0.y = __hip_atomic_load(a0p + ao + 1, __ATOMIC_RELAXED, __HIP_MEMORY_SCOPE_AGENT);
                u1.x = __hip_atomic_load(a1p + ao,     __ATOMIC_RELAXED, __HIP_MEMORY_SCOPE_AGENT);
                u1.y = __hip_atomic_load(a1p + ao + 1, __ATOMIC_RELAXED, __HIP_MEMORY_SCOPE_AGENT);
                bf16x8 a0 = __builtin_bit_cast(bf16x8, u0);
                bf16x8 a1 = __builtin_bit_cast(bf16x8, u1);
                bf16x8 b0 = __builtin_bit_cast(bf16x8, *(const uint4*)(b0p + it * 1024));
                bf16x8 b1 = __builtin_bit_cast(bf16x8, *(const uint4*)(b1p + it * 1024));
                a00 = __builtin_amdgcn_mfma_f32_16x16x32_bf16(a0, b0, a00, 0, 0, 0);
                a01 = __builtin_amdgcn_mfma_f32_16x16x32_bf16(a0, b1, a01, 0, 0, 0);
                a10 = __builtin_amdgcn_mfma_f32_16x16x32_bf16(a1, b0, a10, 0, 0, 0);
                a11 = __builtin_amdgcn_mfma_f32_16x16x32_bf16(a1, b1, a11, 0, 0, 0);
            }
        }
        // ---- cross-wave K reduction (xproj + recurrence together) ----
        {
            float* rw = red + wave * 1024;
#pragma unroll
            for (int r = 0; r < 4; ++r) {
                rw[(quad * 4 + r) * 32 + lcol]           = a00[r];
                rw[(quad * 4 + r) * 32 + 16 + lcol]      = a01[r];
                rw[(16 + quad * 4 + r) * 32 + lcol]      = a10[r];
                rw[(16 + quad * 4 + r) * 32 + 16 + lcol] = a11[r];
            }
        }
        __syncthreads();   // (A) all waves done loading h@{t-1} + red ready
        if (t > 0 && tid == 0)   // signal: this block finished READING h@{t-1}
            __hip_atomic_store(cns_own, (unsigned)t, __ATOMIC_RELAXED, __HIP_MEMORY_SCOPE_AGENT);
        float4 sum;
        {
            const float4 s0v = *(const float4*)(red + 0 * 1024 + tid * 4);
            const float4 s1v = *(const float4*)(red + 1 * 1024 + tid * 4);
            const float4 s2v = *(const float4*)(red + 2 * 1024 + tid * 4);
            const float4 s3v = *(const float4*)(red + 3 * 1024 + tid * 4);
            sum.x = (s0v.x + s1v.x) + (s2v.x + s3v.x);
            sum.y = (s0v.y + s1v.y) + (s2v.y + s3v.y);
            sum.z = (s0v.z + s1v.z) + (s2v.z + s3v.z);
            sum.w = (s0v.w + s1v.w) + (s2v.w + s3v.w);
        }
        float4 v;
        v.x = tanhf(sum.x + b4.x);
        v.y = tanhf(sum.y + b4.y);
        v.z = tanhf(sum.z + b4.z);
        v.w = tanhf(sum.w + b4.w);
        if (t < 255) {
            // dist-2 write-safety: everyone must have READ h@{t-2} (this buffer)
            if (t >= 2) {
                while (__hip_atomic_load(cns_poll, __ATOMIC_RELAXED, __HIP_MEMORY_SCOPE_AGENT) < (unsigned)(t - 1))
                    __builtin_amdgcn_s_sleep(1);
            }
            unsigned short* hc = (t & 1) ? hB : hA;
            unsigned long long pv =
                  (unsigned long long)((unsigned int)f32_to_bf16(v.x) | ((unsigned int)f32_to_bf16(v.y) << 16))
                | ((unsigned long long)((unsigned int)f32_to_bf16(v.z) | ((unsigned int)f32_to_bf16(v.w) << 16)) << 32);
            __hip_atomic_store((unsigned long long*)(hc + hoff), pv,
                               __ATOMIC_RELAXED, __HIP_MEMORY_SCOPE_AGENT);
            __builtin_amdgcn_s_waitcnt(0);   // drain: h@t at coherence point
            __syncthreads();                 // (B) whole block drained (guards red reuse)
            if (tid == 0)                    // publish h@t
                __hip_atomic_store(rdy_own, (unsigned)(t + 1), __ATOMIC_RELAXED, __HIP_MEMORY_SCOPE_AGENT);
        } else {
            *(float4*)(out + (size_t)(m0 + erow) * 2048 + n0 + ecol) = v;
        }
    }
}

// ---------------------------------------------------------------------------
extern "C" void kernel_launch(void* const* d_in, const int* in_sizes, int n_in,
                              void* d_out, int out_size, void* d_ws, size_t ws_size,
                              hipStream_t stream) {
    const float* x     = (const float*)d_in[0];
    const float* w_in  = (const float*)d_in[1];
    const float* w_rec = (const float*)d_in[2];
    const float* bias  = (const float*)d_in[3];
    float* out = (float*)d_out;

    char* ws = (char*)d_ws;
    unsigned short* WT_in  = (unsigned short*)(ws + 134217728);
    unsigned short* WT_rec = (unsigned short*)(ws + 134217728 + 8388608);
    unsigned short* hA     = (unsigned short*)(ws + 150994944);
    unsigned short* hB     = (unsigned short*)(ws + 150994944 + 524288);
    unsigned int*   BAR    = (unsigned int*)(ws + 152043520);

    hipMemsetAsync(BAR, 0, 32768, stream);
    cvt_transpose<<<dim3(1024), dim3(256), 0, stream>>>(w_in,  WT_in);
    cvt_transpose<<<dim3(1024), dim3(256), 0, stream>>>(w_rec, WT_rec);

    void* args[] = {(void*)&x, (void*)&WT_in, (void*)&WT_rec, (void*)&bias,
                    (void*)&hA, (void*)&hB, (void*)&out, (void*)&BAR};
    hipLaunchCooperativeKernel(reinterpret_cast<void*>(rnn_scan),
                               dim3(256), dim3(256), args, 0, stream);
}

// Round 5
// 2446.583 us; speedup vs baseline: 1.6055x; 1.6055x over previous
//
#include <hip/hip_runtime.h>

// T=256, B=128, H=2048. M = T*B = 32768.
// ws layout (bytes):
//   XP     @ 0          : 134217728   (xproj, bf16, [t*128+b][h])
//   WT_in  @ 134217728  : 8388608     (w_in^T bf16, [n][k])
//   WT_rec @ 142606336  : 8388608     (w_rec^T bf16, [n][k])
//   hA     @ 150994944  : 524288      (h fragments, even t)
//   hB     @ 151519232  : 524288      (h fragments, odd t)
//   BAR    @ 152043520  : 32768       (ready flags 16 KB | consumed flags 16 KB)
//   Xb     @ 152076288  : 134217728   (x as bf16, only if ws_size allows)
//
// ROUND 3: reverted round-1 fusion (post-mortem: P = C + max(Xp,lambda);
// Xp ~8us >> lambda, and compiler rematerialized win[] from L2 every step
// at VGPR=132). Scan is byte-identical to the verified 1574us version.
// New: X pre-converted to bf16 (cvt_x) + xproj staged via global_load_lds
// (width 16, linear LDS dest) -- removes staging reg round-trip + in-loop
// cvt VALU (guide m93->m97 lever). Falls back to f32 path if ws too small.

typedef __bf16 bf16x8 __attribute__((ext_vector_type(8)));
typedef float f32x4 __attribute__((ext_vector_type(4)));
typedef unsigned long long ullx2 __attribute__((ext_vector_type(2)));

__device__ __forceinline__ unsigned short f32_to_bf16(float f) {
    unsigned int u = __builtin_bit_cast(unsigned int, f);
    u += 0x7FFFu + ((u >> 16) & 1u);   // round-to-nearest-even
    return (unsigned short)(u >> 16);
}
__device__ __forceinline__ float bf16_to_f32(unsigned short s) {
    unsigned int u = ((unsigned int)s) << 16;
    return __builtin_bit_cast(float, u);
}
__device__ __forceinline__ uint4 pack8(float4 a, float4 b) {
    uint4 r;
    r.x = (unsigned int)f32_to_bf16(a.x) | ((unsigned int)f32_to_bf16(a.y) << 16);
    r.y = (unsigned int)f32_to_bf16(a.z) | ((unsigned int)f32_to_bf16(a.w) << 16);
    r.z = (unsigned int)f32_to_bf16(b.x) | ((unsigned int)f32_to_bf16(b.y) << 16);
    r.w = (unsigned int)f32_to_bf16(b.z) | ((unsigned int)f32_to_bf16(b.w) << 16);
    return r;
}
__device__ __forceinline__ void gload_lds16(const void* g, void* l) {
    __builtin_amdgcn_global_load_lds(
        (const __attribute__((address_space(1))) void*)g,
        (__attribute__((address_space(3))) void*)l, 16, 0, 0);
}

// ---------------------------------------------------------------------------
// Kernel 1: fp32 (2048x2048, [k][n]) -> bf16 transposed ([n][k]) via LDS tile.
// ---------------------------------------------------------------------------
__global__ __launch_bounds__(256)
void cvt_transpose(const float* __restrict__ W, unsigned short* __restrict__ WT) {
    __shared__ unsigned short tile[64][68];
    const int tid = threadIdx.x;
    const int n0 = (blockIdx.x & 31) * 64;
    const int k0 = (blockIdx.x >> 5) * 64;
    const int rr = tid >> 4;
    const int cc = (tid & 15) * 4;
#pragma unroll
    for (int p = 0; p < 4; ++p) {
        const int k = rr + p * 16;
        const float4 v = *(const float4*)(W + (size_t)(k0 + k) * 2048 + n0 + cc);
        tile[cc + 0][k] = f32_to_bf16(v.x);
        tile[cc + 1][k] = f32_to_bf16(v.y);
        tile[cc + 2][k] = f32_to_bf16(v.z);
        tile[cc + 3][k] = f32_to_bf16(v.w);
    }
    __syncthreads();
#pragma unroll
    for (int p = 0; p < 4; ++p) {
        const int n = rr + p * 16;
        unsigned int lo = (unsigned int)tile[n][cc]     | ((unsigned int)tile[n][cc + 1] << 16);
        unsigned int hi = (unsigned int)tile[n][cc + 2] | ((unsigned int)tile[n][cc + 3] << 16);
        uint2 ov; ov.x = lo; ov.y = hi;
        *(uint2*)(WT + (size_t)(n0 + n) * 2048 + k0 + cc) = ov;
    }
}

// ---------------------------------------------------------------------------
// Kernel 1b: X f32 -> bf16 (same layout), grid-stride, 8 elems/thread/iter.
// 67108864 elems = 8388608 groups of 8; 2048x256 threads -> 16 iters.
// ---------------------------------------------------------------------------
__global__ __launch_bounds__(256)
void cvt_x(const float* __restrict__ X, unsigned short* __restrict__ Xb) {
    const size_t stride = 2048 * 256;
    for (size_t i = (size_t)blockIdx.x * 256 + threadIdx.x; i < 8388608; i += stride) {
        const float4 a = *(const float4*)(X + i * 8);
        const float4 b = *(const float4*)(X + i * 8 + 4);
        const uint4 r = pack8(a, b);
        *(uint4*)(Xb + i * 8) = r;
    }
}

// ---------------------------------------------------------------------------
// Kernel 2a: xproj GEMM, f32 A path (verified round-0 code, fallback).
// C[m][n] = sum_k X[m][k] * w_in[k][n], stored bf16. 128x128 tile, BK=32.
// ---------------------------------------------------------------------------
__global__ __launch_bounds__(256, 2)
void xproj_gemm_f32(const float* __restrict__ X, const unsigned short* __restrict__ WT,
                    unsigned short* __restrict__ XP) {
    __shared__ unsigned short As[128 * 32];
    __shared__ unsigned short Bs[128 * 32];
    const int tid  = threadIdx.x;
    const int bid  = blockIdx.x;
    const int m0   = (bid >> 4) * 128;
    const int n0   = (bid & 15) * 128;
    const int lane = tid & 63;
    const int wave = tid >> 6;
    const int wm   = (wave & 1) * 64;
    const int wn   = (wave >> 1) * 64;
    const int lcol = lane & 15;
    const int quad = lane >> 4;

    const int ar = tid >> 3;
    const int ac = (tid & 7) * 4;
    const int br = tid >> 1;
    const int bc = (tid & 1) * 16;

    f32x4 acc[4][4] = {};

    for (int kk = 0; kk < 2048; kk += 32) {
#pragma unroll
        for (int p = 0; p < 4; ++p) {
            const int r = ar + p * 32;
            const float4 v = *(const float4*)(X + (size_t)(m0 + r) * 2048 + kk + ac);
            unsigned int lo = (unsigned int)f32_to_bf16(v.x) | ((unsigned int)f32_to_bf16(v.y) << 16);
            unsigned int hi = (unsigned int)f32_to_bf16(v.z) | ((unsigned int)f32_to_bf16(v.w) << 16);
            uint2 w; w.x = lo; w.y = hi;
            *(uint2*)(As + r * 32 + ac) = w;
        }
        {
            const unsigned short* g = WT + (size_t)(n0 + br) * 2048 + kk + bc;
            const uint4 v0 = *(const uint4*)(g);
            const uint4 v1 = *(const uint4*)(g + 8);
            *(uint4*)(Bs + br * 32 + bc)     = v0;
            *(uint4*)(Bs + br * 32 + bc + 8) = v1;
        }
        __syncthreads();
        bf16x8 af[4], bf[4];
#pragma unroll
        for (int i = 0; i < 4; ++i)
            af[i] = __builtin_bit_cast(bf16x8, *(const uint4*)(As + (wm + i * 16 + lcol) * 32 + quad * 8));
#pragma unroll
        for (int j = 0; j < 4; ++j)
            bf[j] = __builtin_bit_cast(bf16x8, *(const uint4*)(Bs + (wn + j * 16 + lcol) * 32 + quad * 8));
#pragma unroll
        for (int i = 0; i < 4; ++i)
#pragma unroll
            for (int j = 0; j < 4; ++j)
                acc[i][j] = __builtin_amdgcn_mfma_f32_16x16x32_bf16(af[i], bf[j], acc[i][j], 0, 0, 0);
        __syncthreads();
    }
#pragma unroll
    for (int i = 0; i < 4; ++i)
#pragma unroll
        for (int j = 0; j < 4; ++j) {
            const int row = m0 + wm + i * 16 + quad * 4;
            const int col = n0 + wn + j * 16 + lcol;
#pragma unroll
            for (int r = 0; r < 4; ++r)
                XP[(size_t)(row + r) * 2048 + col] = f32_to_bf16(acc[i][j][r]);
        }
}

// ---------------------------------------------------------------------------
// Kernel 2b: xproj GEMM, bf16 A path via global_load_lds (width 16).
// Same tile/fragment/epilogue as 2a; only the staging differs.
// Staging per K-step: per wave 2 insts for A, 2 for B; each inst moves
// 64 lanes x 16B = 1 KB into a linear LDS range (dest = wave-uniform base,
// lane offset auto = lane*16B; global src per-lane).
//   inst(w,q): lane i -> row = w*32 + q*16 + (i>>2), colchunk = (i&3)*8
//   LDS bytes: w*2048 + q*1024 + i*16  ==  row*64 + colchunk*2   (checked)
// ---------------------------------------------------------------------------
__global__ __launch_bounds__(256, 2)
void xproj_gemm_bf16(const unsigned short* __restrict__ Xb,
                     const unsigned short* __restrict__ WT,
                     unsigned short* __restrict__ XP) {
    __shared__ unsigned short As[128 * 32];
    __shared__ unsigned short Bs[128 * 32];
    const int tid  = threadIdx.x;
    const int bid  = blockIdx.x;
    const int m0   = (bid >> 4) * 128;
    const int n0   = (bid & 15) * 128;
    const int lane = tid & 63;
    const int wave = tid >> 6;
    const int wm   = (wave & 1) * 64;
    const int wn   = (wave >> 1) * 64;
    const int lcol = lane & 15;
    const int quad = lane >> 4;

    const int srow = lane >> 2;        // 0..15
    const int scol = (lane & 3) * 8;   // shorts

    f32x4 acc[4][4] = {};

    for (int kk = 0; kk < 2048; kk += 32) {
#pragma unroll
        for (int q = 0; q < 2; ++q) {
            const int r = wave * 32 + q * 16 + srow;
            gload_lds16(Xb + (size_t)(m0 + r) * 2048 + kk + scol,
                        As + wave * 1024 + q * 512);
            gload_lds16(WT + (size_t)(n0 + r) * 2048 + kk + scol,
                        Bs + wave * 1024 + q * 512);
        }
        __syncthreads();
        bf16x8 af[4], bf[4];
#pragma unroll
        for (int i = 0; i < 4; ++i)
            af[i] = __builtin_bit_cast(bf16x8, *(const uint4*)(As + (wm + i * 16 + lcol) * 32 + quad * 8));
#pragma unroll
        for (int j = 0; j < 4; ++j)
            bf[j] = __builtin_bit_cast(bf16x8, *(const uint4*)(Bs + (wn + j * 16 + lcol) * 32 + quad * 8));
#pragma unroll
        for (int i = 0; i < 4; ++i)
#pragma unroll
            for (int j = 0; j < 4; ++j)
                acc[i][j] = __builtin_amdgcn_mfma_f32_16x16x32_bf16(af[i], bf[j], acc[i][j], 0, 0, 0);
        __syncthreads();
    }
#pragma unroll
    for (int i = 0; i < 4; ++i)
#pragma unroll
        for (int j = 0; j < 4; ++j) {
            const int row = m0 + wm + i * 16 + quad * 4;
            const int col = n0 + wn + j * 16 + lcol;
#pragma unroll
            for (int r = 0; r < 4; ++r)
                XP[(size_t)(row + r) * 2048 + col] = f32_to_bf16(acc[i][j][r]);
        }
}

// ---------------------------------------------------------------------------
// Kernel 3: persistent recurrence (VERIFIED round-0 version, unchanged).
// 256 blocks x 256 threads. g = (bid&7)>>1 (XCD-affine batch group),
// nb = column block 0..63. Wave w consumes kb in [16w,16w+16).
// h moves via coalesced 8B relaxed agent atomics (L3-coherent).
// Flags: rdy[g][nb]=t+1 (h@t at L3), cns[g][nb]=t (done reading h@{t-1}).
// ---------------------------------------------------------------------------
__global__ __launch_bounds__(256, 1)
void rnn_scan(const unsigned short* __restrict__ XP,
              const unsigned short* __restrict__ WT,
              const float* __restrict__ bias,
              unsigned short* __restrict__ hA,
              unsigned short* __restrict__ hB,
              float* __restrict__ out,
              unsigned int* __restrict__ bar) {
    __shared__ unsigned short Ws[64 * 2 * 512];   // fragment-major, 128 KB
    __shared__ float red[4 * 1024];               // 4 wave-partials of 32x32
    const int tid  = threadIdx.x;
    const int bid  = blockIdx.x;
    const int g    = (bid & 7) >> 1;               // batch group (XCD-affine)
    const int nb   = ((bid >> 3) << 1) | (bid & 1);// column block 0..63
    const int n0   = nb * 32;
    const int m0   = g * 32;
    const int lane = tid & 63;
    const int wave = tid >> 6;
    const int lcol = lane & 15;
    const int quad = lane >> 4;

    unsigned int* rdy_own = bar + (g * 64 + nb) * 16;
    unsigned int* cns_own = bar + 4096 + (g * 64 + nb) * 16;
    const unsigned int* rdy_poll = bar + (g * 64 + wave * 16 + lcol) * 16;  // my chunk's producers
    const unsigned int* cns_poll = bar + 4096 + (g * 64 + lane) * 16;       // all 64 group blocks

    // stage w_rec^T slice into LDS in B-fragment-major layout:
    // frag (kb, half): lane L holds B[n = 16*half + (L&15)][k = 32*kb + 8*(L>>4) + j]
    {
        const int r    = tid >> 3;          // local col n 0..31
        const int half = r >> 4;
        const int lc   = r & 15;
        const int ch   = (tid & 7) * 256;   // k start
        const unsigned short* src = WT + (size_t)(n0 + r) * 2048 + ch;
#pragma unroll
        for (int c = 0; c < 32; ++c) {
            const int k    = ch + c * 8;
            const int kb   = k >> 5;
            const int qd   = (k & 31) >> 3;
            unsigned short* dst = Ws + (kb * 2 + half) * 512 + (qd * 16 + lc) * 8;
            *(uint4*)dst = *(const uint4*)(src + c * 8);
        }
    }
    const int erow = tid >> 3;          // epilogue: 4 elems per thread
    const int ecol = (tid & 7) * 4;
    const float4 b4 = *(const float4*)(bias + n0 + ecol);
    // producer store offset (shorts) into fragment-major h
    const size_t hoff = ((size_t)(g * 64 + nb) * 2 + (erow >> 4)) * 512
                        + (size_t)((ecol >> 3) * 16 + (erow & 15)) * 8 + (ecol & 7);
    // consumer load base (ull units): frags (g, kb=wave*16+it, half)
    const size_t s0 = (size_t)(g * 64 + wave * 16) * 256 + lane * 2;
    __syncthreads();

    for (int t = 0; t < 256; ++t) {
        const uint2 xpu = *(const uint2*)(XP + (size_t)(t * 128 + m0 + erow) * 2048 + n0 + ecol);
        float4 sum = {0.f, 0.f, 0.f, 0.f};
        if (t > 0) {
            // wait for MY chunk's 16 producers to have h@{t-1} at L3
            while (__hip_atomic_load(rdy_poll, __ATOMIC_RELAXED, __HIP_MEMORY_SCOPE_AGENT) < (unsigned)t)
                __builtin_amdgcn_s_sleep(1);
            __builtin_amdgcn_fence(__ATOMIC_ACQUIRE, "workgroup");

            const unsigned long long* hp =
                (const unsigned long long*)((t & 1) ? hA : hB);
            f32x4 a00 = {}, a01 = {}, a10 = {}, a11 = {};
            const unsigned long long* a0p = hp + s0;          // half 0
            const unsigned long long* a1p = hp + s0 + 128;    // half 1
            const unsigned short* b0p = Ws + (wave * 16 * 2) * 512 + lane * 8;  // half 0
            const unsigned short* b1p = b0p + 512;                              // half 1
#pragma unroll
            for (int it = 0; it < 16; ++it) {
                const size_t ao = (size_t)it * 256;
                ullx2 u0, u1;
                u0.x = __hip_atomic_load(a0p + ao,     __ATOMIC_RELAXED, __HIP_MEMORY_SCOPE_AGENT);
                u0.y = __hip_atomic_load(a0p + ao + 1, __ATOMIC_RELAXED, __HIP_MEMORY_SCOPE_AGENT);
                u1.x = __hip_atomic_load(a1p + ao,     __ATOMIC_RELAXED, __HIP_MEMORY_SCOPE_AGENT);
                u1.y = __hip_atomic_load(a1p + ao + 1, __ATOMIC_RELAXED, __HIP_MEMORY_SCOPE_AGENT);
                bf16x8 a0 = __builtin_bit_cast(bf16x8, u0);
                bf16x8 a1 = __builtin_bit_cast(bf16x8, u1);
                bf16x8 b0 = __builtin_bit_cast(bf16x8, *(const uint4*)(b0p + it * 1024));
                bf16x8 b1 = __builtin_bit_cast(bf16x8, *(const uint4*)(b1p + it * 1024));
                a00 = __builtin_amdgcn_mfma_f32_16x16x32_bf16(a0, b0, a00, 0, 0, 0);
                a01 = __builtin_amdgcn_mfma_f32_16x16x32_bf16(a0, b1, a01, 0, 0, 0);
                a10 = __builtin_amdgcn_mfma_f32_16x16x32_bf16(a1, b0, a10, 0, 0, 0);
                a11 = __builtin_amdgcn_mfma_f32_16x16x32_bf16(a1, b1, a11, 0, 0, 0);
            }
            float* rw = red + wave * 1024;
#pragma unroll
            for (int r = 0; r < 4; ++r) {
                rw[(quad * 4 + r) * 32 + lcol]           = a00[r];
                rw[(quad * 4 + r) * 32 + 16 + lcol]      = a01[r];
                rw[(16 + quad * 4 + r) * 32 + lcol]      = a10[r];
                rw[(16 + quad * 4 + r) * 32 + 16 + lcol] = a11[r];
            }
            __syncthreads();   // (A) all waves done loading h@{t-1} + red ready
            if (tid == 0)      // signal: this block finished READING h@{t-1}
                __hip_atomic_store(cns_own, (unsigned)t, __ATOMIC_RELAXED, __HIP_MEMORY_SCOPE_AGENT);
            const float4 s0v = *(const float4*)(red + 0 * 1024 + tid * 4);
            const float4 s1v = *(const float4*)(red + 1 * 1024 + tid * 4);
            const float4 s2v = *(const float4*)(red + 2 * 1024 + tid * 4);
            const float4 s3v = *(const float4*)(red + 3 * 1024 + tid * 4);
            sum.x = (s0v.x + s1v.x) + (s2v.x + s3v.x);
            sum.y = (s0v.y + s1v.y) + (s2v.y + s3v.y);
            sum.z = (s0v.z + s1v.z) + (s2v.z + s3v.z);
            sum.w = (s0v.w + s1v.w) + (s2v.w + s3v.w);
        }
        float4 v;
        v.x = tanhf(bf16_to_f32((unsigned short)(xpu.x & 0xFFFFu)) + sum.x + b4.x);
        v.y = tanhf(bf16_to_f32((unsigned short)(xpu.x >> 16))     + sum.y + b4.y);
        v.z = tanhf(bf16_to_f32((unsigned short)(xpu.y & 0xFFFFu)) + sum.z + b4.z);
        v.w = tanhf(bf16_to_f32((unsigned short)(xpu.y >> 16))     + sum.w + b4.w);
        if (t < 255) {
            // dist-2 write-safety: everyone must have READ h@{t-2} (this buffer)
            if (t >= 2) {
                while (__hip_atomic_load(cns_poll, __ATOMIC_RELAXED, __HIP_MEMORY_SCOPE_AGENT) < (unsigned)(t - 1))
                    __builtin_amdgcn_s_sleep(1);
            }
            unsigned short* hc = (t & 1) ? hB : hA;
            unsigned long long pv =
                  (unsigned long long)((unsigned int)f32_to_bf16(v.x) | ((unsigned int)f32_to_bf16(v.y) << 16))
                | ((unsigned long long)((unsigned int)f32_to_bf16(v.z) | ((unsigned int)f32_to_bf16(v.w) << 16)) << 32);
            __hip_atomic_store((unsigned long long*)(hc + hoff), pv,
                               __ATOMIC_RELAXED, __HIP_MEMORY_SCOPE_AGENT);
            __builtin_amdgcn_s_waitcnt(0);   // drain: h@t at coherence point
            __syncthreads();                 // (B) whole block drained (guards red reuse)
            if (tid == 0)                    // publish h@t
                __hip_atomic_store(rdy_own, (unsigned)(t + 1), __ATOMIC_RELAXED, __HIP_MEMORY_SCOPE_AGENT);
        } else {
            *(float4*)(out + (size_t)(m0 + erow) * 2048 + n0 + ecol) = v;
        }
    }
}

// ---------------------------------------------------------------------------
extern "C" void kernel_launch(void* const* d_in, const int* in_sizes, int n_in,
                              void* d_out, int out_size, void* d_ws, size_t ws_size,
                              hipStream_t stream) {
    const float* x     = (const float*)d_in[0];
    const float* w_in  = (const float*)d_in[1];
    const float* w_rec = (const float*)d_in[2];
    const float* bias  = (const float*)d_in[3];
    float* out = (float*)d_out;

    char* ws = (char*)d_ws;
    unsigned short* XP     = (unsigned short*)(ws);
    unsigned short* WT_in  = (unsigned short*)(ws + 134217728);
    unsigned short* WT_rec = (unsigned short*)(ws + 134217728 + 8388608);
    unsigned short* hA     = (unsigned short*)(ws + 150994944);
    unsigned short* hB     = (unsigned short*)(ws + 150994944 + 524288);
    unsigned int*   BAR    = (unsigned int*)(ws + 152043520);
    unsigned short* Xb     = (unsigned short*)(ws + 152076288);

    hipMemsetAsync(BAR, 0, 32768, stream);
    cvt_transpose<<<dim3(1024), dim3(256), 0, stream>>>(w_in,  WT_in);
    cvt_transpose<<<dim3(1024), dim3(256), 0, stream>>>(w_rec, WT_rec);

    if (ws_size >= 286294016ull) {
        cvt_x<<<dim3(2048), dim3(256), 0, stream>>>(x, Xb);
        xproj_gemm_bf16<<<dim3(4096), dim3(256), 0, stream>>>(Xb, WT_in, XP);
    } else {
        xproj_gemm_f32<<<dim3(4096), dim3(256), 0, stream>>>(x, WT_in, XP);
    }

    void* args[] = {(void*)&XP, (void*)&WT_rec, (void*)&bias,
                    (void*)&hA, (void*)&hB, (void*)&out, (void*)&BAR};
    hipLaunchCooperativeKernel(reinterpret_cast<void*>(rnn_scan),
                               dim3(256), dim3(256), args, 0, stream);
}

// Round 6
// 2286.283 us; speedup vs baseline: 1.7181x; 1.0701x over previous
//
#include <hip/hip_runtime.h>

// T=256, B=128, H=2048. M = T*B = 32768.
// ws layout (bytes):
//   XP     @ 0          : 134217728   (xproj/h overlay, bf16, block-major slices)
//   WT_in  @ 134217728  : 8388608     (w_in^T bf16, [n][k])
//   WT_rec @ 142606336  : 8388608     (w_rec^T bf16, [n][k])
//   BAR    @ 152043520  : 32768       (ready flags 16 KB; rest unused)
//   Xb     @ 152076288  : 134217728   (x as bf16, ONLY if ws_size >= 286 MB)
//
// ROUND 5 CHANGE (h-in-XP overlay):
//   XP is stored block-major: slice(t,g,nb) = 2 KB at ((t*4+g)*64+nb)*1024
//   shorts, in MFMA-A-fragment layout: half h (1KB each): lane*16B, with
//   element row = 16*half + (lane&15), col = 8*(lane>>4) + j.
//   Step t: block (g,nb) reads its own slice (bypass/atomic loads -> slice
//   lines never enter any cache), computes h@t, and atomically stores h@t
//   INTO THE SAME SLICE (to L3). Consumers at t+1 read h fragments with
//   PLAIN loads: address unique per t -> no stale copies possible; first
//   reader per XCD pulls L3->L2, co-XCD blocks hit L2 (32x less L3 traffic).
//   cns (consumed) flags deleted: no buffer reuse -> no WAR hazard.
//   Numerics bit-identical to the verified 2-buffer scan.

typedef __bf16 bf16x8 __attribute__((ext_vector_type(8)));
typedef float f32x4 __attribute__((ext_vector_type(4)));

__device__ __forceinline__ unsigned short f32_to_bf16(float f) {
    unsigned int u = __builtin_bit_cast(unsigned int, f);
    u += 0x7FFFu + ((u >> 16) & 1u);   // round-to-nearest-even
    return (unsigned short)(u >> 16);
}
__device__ __forceinline__ float bf16_to_f32(unsigned short s) {
    unsigned int u = ((unsigned int)s) << 16;
    return __builtin_bit_cast(float, u);
}
__device__ __forceinline__ uint4 pack8(float4 a, float4 b) {
    uint4 r;
    r.x = (unsigned int)f32_to_bf16(a.x) | ((unsigned int)f32_to_bf16(a.y) << 16);
    r.y = (unsigned int)f32_to_bf16(a.z) | ((unsigned int)f32_to_bf16(a.w) << 16);
    r.z = (unsigned int)f32_to_bf16(b.x) | ((unsigned int)f32_to_bf16(b.y) << 16);
    r.w = (unsigned int)f32_to_bf16(b.z) | ((unsigned int)f32_to_bf16(b.w) << 16);
    return r;
}
__device__ __forceinline__ void gload_lds16(const void* g, void* l) {
    __builtin_amdgcn_global_load_lds(
        (const __attribute__((address_space(1))) void*)g,
        (__attribute__((address_space(3))) void*)l, 16, 0, 0);
}

// ---------------------------------------------------------------------------
// Kernel 1: fp32 (2048x2048, [k][n]) -> bf16 transposed ([n][k]) via LDS tile.
// ---------------------------------------------------------------------------
__global__ __launch_bounds__(256)
void cvt_transpose(const float* __restrict__ W, unsigned short* __restrict__ WT) {
    __shared__ unsigned short tile[64][68];
    const int tid = threadIdx.x;
    const int n0 = (blockIdx.x & 31) * 64;
    const int k0 = (blockIdx.x >> 5) * 64;
    const int rr = tid >> 4;
    const int cc = (tid & 15) * 4;
#pragma unroll
    for (int p = 0; p < 4; ++p) {
        const int k = rr + p * 16;
        const float4 v = *(const float4*)(W + (size_t)(k0 + k) * 2048 + n0 + cc);
        tile[cc + 0][k] = f32_to_bf16(v.x);
        tile[cc + 1][k] = f32_to_bf16(v.y);
        tile[cc + 2][k] = f32_to_bf16(v.z);
        tile[cc + 3][k] = f32_to_bf16(v.w);
    }
    __syncthreads();
#pragma unroll
    for (int p = 0; p < 4; ++p) {
        const int n = rr + p * 16;
        unsigned int lo = (unsigned int)tile[n][cc]     | ((unsigned int)tile[n][cc + 1] << 16);
        unsigned int hi = (unsigned int)tile[n][cc + 2] | ((unsigned int)tile[n][cc + 3] << 16);
        uint2 ov; ov.x = lo; ov.y = hi;
        *(uint2*)(WT + (size_t)(n0 + n) * 2048 + k0 + cc) = ov;
    }
}

// ---------------------------------------------------------------------------
// Kernel 1b: X f32 -> bf16 (same layout), grid-stride.
// ---------------------------------------------------------------------------
__global__ __launch_bounds__(256)
void cvt_x(const float* __restrict__ X, unsigned short* __restrict__ Xb) {
    const size_t stride = 2048 * 256;
    for (size_t i = (size_t)blockIdx.x * 256 + threadIdx.x; i < 8388608; i += stride) {
        const float4 a = *(const float4*)(X + i * 8);
        const float4 b = *(const float4*)(X + i * 8 + 4);
        const uint4 r = pack8(a, b);
        *(uint4*)(Xb + i * 8) = r;
    }
}

// Shared epilogue: write acc into block-major fragment-layout XP.
// row = t*128 + b, b = wm+i*16+quad*4+r; col = n0+wn+j*16+lcol.
// slice(t,g,nb) base + (rr>>4)*512 + ((cc>>3)*16 + (rr&15))*8 + (cc&7), rr=b&31.
#define XPROJ_EPILOGUE()                                                        \
    {                                                                           \
        const int t = bid >> 4;                                                 \
        _Pragma("unroll")                                                       \
        for (int i = 0; i < 4; ++i) {                                           \
            const int brow = wm + i * 16;          /* multiple of 16 */         \
            const int g2   = brow >> 5;                                         \
            const int h2   = (brow & 31) >> 4;                                  \
            _Pragma("unroll")                                                   \
            for (int j = 0; j < 4; ++j) {                                       \
                const int col = n0 + wn + j * 16 + lcol;                        \
                const int nb2 = col >> 5;                                       \
                const int cc  = col & 31;                                       \
                const size_t base = (((size_t)t * 4 + g2) * 64 + nb2) * 1024    \
                                  + (size_t)h2 * 512                            \
                                  + (size_t)(cc >> 3) * 128 + (cc & 7);         \
                _Pragma("unroll")                                               \
                for (int r = 0; r < 4; ++r)                                     \
                    XP[base + (size_t)(quad * 4 + r) * 8] =                     \
                        f32_to_bf16(acc[i][j][r]);                              \
            }                                                                   \
        }                                                                       \
    }

// ---------------------------------------------------------------------------
// Kernel 2a: xproj GEMM, f32 A path (fallback). 128x128 tile, BK=32.
// ---------------------------------------------------------------------------
__global__ __launch_bounds__(256, 2)
void xproj_gemm_f32(const float* __restrict__ X, const unsigned short* __restrict__ WT,
                    unsigned short* __restrict__ XP) {
    __shared__ unsigned short As[128 * 32];
    __shared__ unsigned short Bs[128 * 32];
    const int tid  = threadIdx.x;
    const int bid  = blockIdx.x;
    const int m0   = (bid >> 4) * 128;
    const int n0   = (bid & 15) * 128;
    const int lane = tid & 63;
    const int wave = tid >> 6;
    const int wm   = (wave & 1) * 64;
    const int wn   = (wave >> 1) * 64;
    const int lcol = lane & 15;
    const int quad = lane >> 4;

    const int ar = tid >> 3;
    const int ac = (tid & 7) * 4;
    const int br = tid >> 1;
    const int bc = (tid & 1) * 16;

    f32x4 acc[4][4] = {};

    for (int kk = 0; kk < 2048; kk += 32) {
#pragma unroll
        for (int p = 0; p < 4; ++p) {
            const int r = ar + p * 32;
            const float4 v = *(const float4*)(X + (size_t)(m0 + r) * 2048 + kk + ac);
            unsigned int lo = (unsigned int)f32_to_bf16(v.x) | ((unsigned int)f32_to_bf16(v.y) << 16);
            unsigned int hi = (unsigned int)f32_to_bf16(v.z) | ((unsigned int)f32_to_bf16(v.w) << 16);
            uint2 w; w.x = lo; w.y = hi;
            *(uint2*)(As + r * 32 + ac) = w;
        }
        {
            const unsigned short* g = WT + (size_t)(n0 + br) * 2048 + kk + bc;
            const uint4 v0 = *(const uint4*)(g);
            const uint4 v1 = *(const uint4*)(g + 8);
            *(uint4*)(Bs + br * 32 + bc)     = v0;
            *(uint4*)(Bs + br * 32 + bc + 8) = v1;
        }
        __syncthreads();
        bf16x8 af[4], bf[4];
#pragma unroll
        for (int i = 0; i < 4; ++i)
            af[i] = __builtin_bit_cast(bf16x8, *(const uint4*)(As + (wm + i * 16 + lcol) * 32 + quad * 8));
#pragma unroll
        for (int j = 0; j < 4; ++j)
            bf[j] = __builtin_bit_cast(bf16x8, *(const uint4*)(Bs + (wn + j * 16 + lcol) * 32 + quad * 8));
#pragma unroll
        for (int i = 0; i < 4; ++i)
#pragma unroll
            for (int j = 0; j < 4; ++j)
                acc[i][j] = __builtin_amdgcn_mfma_f32_16x16x32_bf16(af[i], bf[j], acc[i][j], 0, 0, 0);
        __syncthreads();
    }
    XPROJ_EPILOGUE()
}

// ---------------------------------------------------------------------------
// Kernel 2b: xproj GEMM, bf16 A path via global_load_lds (width 16).
// Only runs if ws_size grants the Xb buffer.
// ---------------------------------------------------------------------------
__global__ __launch_bounds__(256, 2)
void xproj_gemm_bf16(const unsigned short* __restrict__ Xb,
                     const unsigned short* __restrict__ WT,
                     unsigned short* __restrict__ XP) {
    __shared__ unsigned short As[128 * 32];
    __shared__ unsigned short Bs[128 * 32];
    const int tid  = threadIdx.x;
    const int bid  = blockIdx.x;
    const int m0   = (bid >> 4) * 128;
    const int n0   = (bid & 15) * 128;
    const int lane = tid & 63;
    const int wave = tid >> 6;
    const int wm   = (wave & 1) * 64;
    const int wn   = (wave >> 1) * 64;
    const int lcol = lane & 15;
    const int quad = lane >> 4;

    const int srow = lane >> 2;        // 0..15
    const int scol = (lane & 3) * 8;   // shorts

    f32x4 acc[4][4] = {};

    for (int kk = 0; kk < 2048; kk += 32) {
#pragma unroll
        for (int q = 0; q < 2; ++q) {
            const int r = wave * 32 + q * 16 + srow;
            gload_lds16(Xb + (size_t)(m0 + r) * 2048 + kk + scol,
                        As + wave * 1024 + q * 512);
            gload_lds16(WT + (size_t)(n0 + r) * 2048 + kk + scol,
                        Bs + wave * 1024 + q * 512);
        }
        __syncthreads();
        bf16x8 af[4], bf[4];
#pragma unroll
        for (int i = 0; i < 4; ++i)
            af[i] = __builtin_bit_cast(bf16x8, *(const uint4*)(As + (wm + i * 16 + lcol) * 32 + quad * 8));
#pragma unroll
        for (int j = 0; j < 4; ++j)
            bf[j] = __builtin_bit_cast(bf16x8, *(const uint4*)(Bs + (wn + j * 16 + lcol) * 32 + quad * 8));
#pragma unroll
        for (int i = 0; i < 4; ++i)
#pragma unroll
            for (int j = 0; j < 4; ++j)
                acc[i][j] = __builtin_amdgcn_mfma_f32_16x16x32_bf16(af[i], bf[j], acc[i][j], 0, 0, 0);
        __syncthreads();
    }
    XPROJ_EPILOGUE()
}

// ---------------------------------------------------------------------------
// Kernel 3: persistent recurrence, h-in-XP overlay.
// 256 blocks x 256 threads. g = (bid&7)>>1 (XCD-affine), nb = col block 0..63.
// Wave w consumes kb in [16w,16w+16). rdy[g][nb]=t+1 <=> h@t at L3.
// h@t lives in XP slice (t,g,nb): unique address per t -> plain cached
// consumer loads are safe (L2-shared per XCD); own-slice XP read is bypass
// (atomic) so no cache ever holds the pre-write version; no cns flags.
// ---------------------------------------------------------------------------
__global__ __launch_bounds__(256, 1)
void rnn_scan(unsigned short* __restrict__ XP,
              const unsigned short* __restrict__ WT,
              const float* __restrict__ bias,
              float* __restrict__ out,
              unsigned int* __restrict__ bar) {
    __shared__ unsigned short Ws[64 * 2 * 512];   // fragment-major, 128 KB
    __shared__ float red[4 * 1024];               // 4 wave-partials of 32x32
    const int tid  = threadIdx.x;
    const int bid  = blockIdx.x;
    const int g    = (bid & 7) >> 1;               // batch group (XCD-affine)
    const int nb   = ((bid >> 3) << 1) | (bid & 1);// column block 0..63
    const int n0   = nb * 32;
    const int m0   = g * 32;
    const int lane = tid & 63;
    const int wave = tid >> 6;
    const int lcol = lane & 15;
    const int quad = lane >> 4;

    unsigned int* rdy_own = bar + (g * 64 + nb) * 16;
    const unsigned int* rdy_poll = bar + (g * 64 + wave * 16 + lcol) * 16;  // my chunk's producers

    // stage w_rec^T slice into LDS in B-fragment-major layout:
    // frag (kb, half): lane L holds B[n = 16*half + (L&15)][k = 32*kb + 8*(L>>4) + j]
    {
        const int r    = tid >> 3;          // local col n 0..31
        const int half = r >> 4;
        const int lc   = r & 15;
        const int ch   = (tid & 7) * 256;   // k start
        const unsigned short* src = WT + (size_t)(n0 + r) * 2048 + ch;
#pragma unroll
        for (int c = 0; c < 32; ++c) {
            const int k    = ch + c * 8;
            const int kb   = k >> 5;
            const int qd   = (k & 31) >> 3;
            unsigned short* dst = Ws + (kb * 2 + half) * 512 + (qd * 16 + lc) * 8;
            *(uint4*)dst = *(const uint4*)(src + c * 8);
        }
    }
    const int erow = tid >> 3;          // epilogue: 4 elems per thread
    const int ecol = (tid & 7) * 4;
    const float4 b4 = *(const float4*)(bias + n0 + ecol);
    // in-slice offset (shorts) of this thread's 4 elems (8 B aligned)
    const size_t eoff = (size_t)(erow >> 4) * 512
                      + (size_t)((ecol >> 3) * 16 + (erow & 15)) * 8 + (ecol & 7);
    __syncthreads();

    for (int t = 0; t < 256; ++t) {
        unsigned short* slice_own = XP + (((size_t)t * 4 + g) * 64 + nb) * 1024;
        // xproj read: bypass load keeps own-slice lines out of L1/L2 so the
        // later h@t write leaves no stale copy anywhere.
        const unsigned long long xp8 = __hip_atomic_load(
            (const unsigned long long*)(slice_own + eoff),
            __ATOMIC_RELAXED, __HIP_MEMORY_SCOPE_AGENT);
        const uint2 xpu = __builtin_bit_cast(uint2, xp8);
        float4 sum = {0.f, 0.f, 0.f, 0.f};
        if (t > 0) {
            // wait for MY chunk's 16 producers to have h@{t-1} at L3
            while (__hip_atomic_load(rdy_poll, __ATOMIC_RELAXED, __HIP_MEMORY_SCOPE_AGENT) < (unsigned)t)
                __builtin_amdgcn_s_sleep(1);
            __builtin_amdgcn_fence(__ATOMIC_ACQUIRE, "workgroup");

            // h@{t-1} fragments: PLAIN cached loads (unique addresses per t,
            // L2-shared across co-XCD consumers)
            const unsigned short* hbase =
                XP + (((size_t)(t - 1) * 4 + g) * 64 + wave * 16) * 1024 + lane * 8;
            const unsigned short* b0p = Ws + (wave * 16 * 2) * 512 + lane * 8;  // half 0
            const unsigned short* b1p = b0p + 512;                              // half 1
            f32x4 a00 = {}, a01 = {}, a10 = {}, a11 = {};
#pragma unroll
            for (int it = 0; it < 16; ++it) {
                bf16x8 a0 = __builtin_bit_cast(bf16x8, *(const uint4*)(hbase + it * 1024));
                bf16x8 a1 = __builtin_bit_cast(bf16x8, *(const uint4*)(hbase + it * 1024 + 512));
                bf16x8 b0 = __builtin_bit_cast(bf16x8, *(const uint4*)(b0p + it * 1024));
                bf16x8 b1 = __builtin_bit_cast(bf16x8, *(const uint4*)(b1p + it * 1024));
                a00 = __builtin_amdgcn_mfma_f32_16x16x32_bf16(a0, b0, a00, 0, 0, 0);
                a01 = __builtin_amdgcn_mfma_f32_16x16x32_bf16(a0, b1, a01, 0, 0, 0);
                a10 = __builtin_amdgcn_mfma_f32_16x16x32_bf16(a1, b0, a10, 0, 0, 0);
                a11 = __builtin_amdgcn_mfma_f32_16x16x32_bf16(a1, b1, a11, 0, 0, 0);
            }
            float* rw = red + wave * 1024;
#pragma unroll
            for (int r = 0; r < 4; ++r) {
                rw[(quad * 4 + r) * 32 + lcol]           = a00[r];
                rw[(quad * 4 + r) * 32 + 16 + lcol]      = a01[r];
                rw[(16 + quad * 4 + r) * 32 + lcol]      = a10[r];
                rw[(16 + quad * 4 + r) * 32 + 16 + lcol] = a11[r];
            }
            __syncthreads();   // (A) red ready
            const float4 s0v = *(const float4*)(red + 0 * 1024 + tid * 4);
            const float4 s1v = *(const float4*)(red + 1 * 1024 + tid * 4);
            const float4 s2v = *(const float4*)(red + 2 * 1024 + tid * 4);
            const float4 s3v = *(const float4*)(red + 3 * 1024 + tid * 4);
            sum.x = (s0v.x + s1v.x) + (s2v.x + s3v.x);
            sum.y = (s0v.y + s1v.y) + (s2v.y + s3v.y);
            sum.z = (s0v.z + s1v.z) + (s2v.z + s3v.z);
            sum.w = (s0v.w + s1v.w) + (s2v.w + s3v.w);
        }
        float4 v;
        v.x = tanhf(bf16_to_f32((unsigned short)(xpu.x & 0xFFFFu)) + sum.x + b4.x);
        v.y = tanhf(bf16_to_f32((unsigned short)(xpu.x >> 16))     + sum.y + b4.y);
        v.z = tanhf(bf16_to_f32((unsigned short)(xpu.y & 0xFFFFu)) + sum.z + b4.z);
        v.w = tanhf(bf16_to_f32((unsigned short)(xpu.y >> 16))     + sum.w + b4.w);
        if (t < 255) {
            unsigned long long pv =
                  (unsigned long long)((unsigned int)f32_to_bf16(v.x) | ((unsigned int)f32_to_bf16(v.y) << 16))
                | ((unsigned long long)((unsigned int)f32_to_bf16(v.z) | ((unsigned int)f32_to_bf16(v.w) << 16)) << 32);
            __hip_atomic_store((unsigned long long*)(slice_own + eoff), pv,
                               __ATOMIC_RELAXED, __HIP_MEMORY_SCOPE_AGENT);
            __builtin_amdgcn_s_waitcnt(0);   // drain: h@t at coherence point
            __syncthreads();                 // (B) whole block drained (guards red reuse)
            if (tid == 0)                    // publish h@t
                __hip_atomic_store(rdy_own, (unsigned)(t + 1), __ATOMIC_RELAXED, __HIP_MEMORY_SCOPE_AGENT);
        } else {
            *(float4*)(out + (size_t)(m0 + erow) * 2048 + n0 + ecol) = v;
        }
    }
}

// ---------------------------------------------------------------------------
extern "C" void kernel_launch(void* const* d_in, const int* in_sizes, int n_in,
                              void* d_out, int out_size, void* d_ws, size_t ws_size,
                              hipStream_t stream) {
    const float* x     = (const float*)d_in[0];
    const float* w_in  = (const float*)d_in[1];
    const float* w_rec = (const float*)d_in[2];
    const float* bias  = (const float*)d_in[3];
    float* out = (float*)d_out;

    char* ws = (char*)d_ws;
    unsigned short* XP     = (unsigned short*)(ws);
    unsigned short* WT_in  = (unsigned short*)(ws + 134217728);
    unsigned short* WT_rec = (unsigned short*)(ws + 134217728 + 8388608);
    unsigned int*   BAR    = (unsigned int*)(ws + 152043520);
    unsigned short* Xb     = (unsigned short*)(ws + 152076288);

    hipMemsetAsync(BAR, 0, 32768, stream);
    cvt_transpose<<<dim3(1024), dim3(256), 0, stream>>>(w_in,  WT_in);
    cvt_transpose<<<dim3(1024), dim3(256), 0, stream>>>(w_rec, WT_rec);

    if (ws_size >= 286294016ull) {
        cvt_x<<<dim3(2048), dim3(256), 0, stream>>>(x, Xb);
        xproj_gemm_bf16<<<dim3(4096), dim3(256), 0, stream>>>(Xb, WT_in, XP);
    } else {
        xproj_gemm_f32<<<dim3(4096), dim3(256), 0, stream>>>(x, WT_in, XP);
    }

    void* args[] = {(void*)&XP, (void*)&WT_rec, (void*)&bias,
                    (void*)&out, (void*)&BAR};
    hipLaunchCooperativeKernel(reinterpret_cast<void*>(rnn_scan),
                               dim3(256), dim3(256), args, 0, stream);
}